// Round 2
// 455.880 us; speedup vs baseline: 1.0516x; 1.0516x over previous
//
#include <hip/hip_runtime.h>

#define NN 100000
#define NE 1200000
#define DD 64
#define EPSV 1e-7f

// Native 4-float vector for __builtin_nontemporal_load (HIP float4 is a class
// type the builtin rejects; clang ext_vector_type is accepted).
typedef float nfloat4 __attribute__((ext_vector_type(4)));

// Kernel A: CSR offsets. off[n] = lower_bound(dst, n) for sorted dst; off[NN]=NE.
// Poison-safe: every off[] slot is rewritten each launch.
__global__ __launch_bounds__(256)
void build_offsets(const int* __restrict__ dst, int* __restrict__ off) {
    int i = blockIdx.x * 256 + threadIdx.x;
    if (i >= NE) return;
    int d = dst[i];
    int prev = (i == 0) ? -1 : dst[i - 1];
    for (int n = prev + 1; n <= d; ++n) off[n] = i;
    if (i == NE - 1) {
        for (int n = d + 1; n <= NN; ++n) off[n] = NE;
    }
}

// One wave per destination node. Lane = (eg, cg): eg = lane>>4 picks one of 4
// edges processed concurrently, cg = lane&15 picks 4 channels (float4).
//
// r4/r5 changes vs r3 (479us kernel):
//  - First 16 edges per node are processed in ONE batched round: all src loads
//    issue together, then all ef/nf vector loads, then compute. 2 serial
//    memory round-trips instead of 4.
//  - Tail lanes are exec-masked (zeroed in compute; load clamped to e_start)
//    instead of clamp-loading e_end-1 for every rounded-up slot.
//  - __syncthreads deferred to just before the GEMV (featL is wave-local).
//  - nontemporal loads on the 307MB edge stream + nt store on out: keep the
//    25.6MB node gather table resident in L2/L3.
__global__ __launch_bounds__(256, 4)
void genconv_kernel(const float* __restrict__ node_feats,
                    const float* __restrict__ edge_feats,
                    const float* __restrict__ W,
                    const float* __restrict__ b,
                    const float* __restrict__ scale,
                    const int* __restrict__ src,
                    const int* __restrict__ dst,
                    const int* __restrict__ off,   // may be null -> bin search
                    float* __restrict__ out)
{
    // W^T in LDS, stride 65: read banks (d+lane)%32 -> 2-way aliasing (free).
    __shared__ float Wt[64 * 65];
    __shared__ float featL[4 * 64];      // per-wave feat staging for GEMV
    const int tid = threadIdx.x;

    // Stage W^T. Barrier is deferred until just before the GEMV.
    #pragma unroll
    for (int r = 0; r < 16; ++r) {
        int idx = r * 256 + tid;
        int j = idx >> 6, d = idx & 63;
        Wt[d * 65 + j] = W[idx];
    }

    const int wave = tid >> 6;
    const int lane = tid & 63;
    const int n = blockIdx.x * 4 + wave;
    const bool active = (n < NN);        // grid exact: 25000*4 == NN

    const int eg = lane >> 4;            // edge subgroup 0..3
    const int cg = lane & 15;            // channel group: channels cg*4..cg*4+3
    const float4*  nf4 = (const float4*)node_feats;
    const nfloat4* ef4 = (const nfloat4*)edge_feats;

    float acc = b[lane];                 // early: overlaps edge loop

    if (active) {
        int e_start, e_end;
        if (off) {
            e_start = off[n];
            e_end   = off[n + 1];
        } else {
            int target = (lane < 32) ? n : (n + 1);
            int lo = 0, hi = NE;
            while (lo < hi) {
                int mid = (lo + hi) >> 1;
                if (dst[mid] < target) lo = mid + 1; else hi = mid;
            }
            e_start = __shfl(lo, 0, 64);
            e_end   = __shfl(lo, 32, 64);
        }

        float4 h4 = nf4[(size_t)n * 16 + cg];   // early: independent of edges

        // Max-free softmax-weighted mean (validated r3): agg = sum(v e^v)/sum(e^v),
        // v = relu(h[src]+ef)+eps bounded -> exp safe in fp32.
        float4 ssum = {0.f, 0.f, 0.f, 0.f};
        float4 wsum = {0.f, 0.f, 0.f, 0.f};
        float* sp = (float*)&ssum;
        float* wp = (float*)&wsum;
        const int deg = e_end - e_start;

        if (deg > 0) {
            // ---- Round 1: up to 16 edges, batched loads (2 round trips) ----
            int     sk[4];
            nfloat4 efv[4];
            bool    okv[4];
            #pragma unroll
            for (int u = 0; u < 4; ++u) {
                int i = e_start + u * 4 + eg;
                bool ok = i < e_end;
                okv[u] = ok;
                int ic = ok ? i : e_start;               // stays in-segment
                sk[u]  = src[ic];
                efv[u] = __builtin_nontemporal_load(&ef4[(size_t)ic * 16 + cg]);
            }
            float4 nfv[4];
            #pragma unroll
            for (int u = 0; u < 4; ++u)
                nfv[u] = nf4[(size_t)sk[u] * 16 + cg];   // 4 gathers in flight
            #pragma unroll
            for (int u = 0; u < 4; ++u) {
                const float* np = (const float*)&nfv[u];
                #pragma unroll
                for (int t = 0; t < 4; ++t) {
                    float v = fmaxf(np[t] + efv[u][t], 0.f) + EPSV;
                    float e = okv[u] ? __expf(v) : 0.f;
                    sp[t] += e;
                    wp[t] += e * v;
                }
            }
            // ---- Overflow (deg > 16, ~10% of nodes): rounds of 8 ----
            for (int base = e_start + 16; base < e_end; base += 8) {
                int     sk2[2];
                nfloat4 ef2[2];
                bool    ok2[2];
                #pragma unroll
                for (int u = 0; u < 2; ++u) {
                    int i = base + u * 4 + eg;
                    bool ok = i < e_end;
                    ok2[u] = ok;
                    int ic = ok ? i : base;              // base < e_end
                    sk2[u] = src[ic];
                    ef2[u] = __builtin_nontemporal_load(&ef4[(size_t)ic * 16 + cg]);
                }
                float4 nf2[2];
                #pragma unroll
                for (int u = 0; u < 2; ++u)
                    nf2[u] = nf4[(size_t)sk2[u] * 16 + cg];
                #pragma unroll
                for (int u = 0; u < 2; ++u) {
                    const float* np = (const float*)&nf2[u];
                    #pragma unroll
                    for (int t = 0; t < 4; ++t) {
                        float v = fmaxf(np[t] + ef2[u][t], 0.f) + EPSV;
                        float e = ok2[u] ? __expf(v) : 0.f;
                        sp[t] += e;
                        wp[t] += e * v;
                    }
                }
            }
        }

        // Reduce the 4 edge-subgroups (lanes L, L^16, L^32 hold same channels).
        float4 agg;
        float* ap = (float*)&agg;
        #pragma unroll
        for (int t = 0; t < 4; ++t) {
            sp[t] += __shfl_xor(sp[t], 16, 64);
            sp[t] += __shfl_xor(sp[t], 32, 64);
            wp[t] += __shfl_xor(wp[t], 16, 64);
            wp[t] += __shfl_xor(wp[t], 32, 64);
            ap[t] = (sp[t] > 0.f) ? (wp[t] / sp[t]) : 0.f;   // empty segment -> 0
        }

        // MessageNorm: feat = h + agg * (||h|| * scale / max(||agg||,1e-12))
        float* hp = (float*)&h4;
        float a2 = ap[0]*ap[0] + ap[1]*ap[1] + ap[2]*ap[2] + ap[3]*ap[3];
        float h2 = hp[0]*hp[0] + hp[1]*hp[1] + hp[2]*hp[2] + hp[3]*hp[3];
        #pragma unroll
        for (int o = 8; o >= 1; o >>= 1) {   // sum across the 16 channel groups
            a2 += __shfl_xor(a2, o, 64);
            h2 += __shfl_xor(h2, o, 64);
        }
        float k = sqrtf(h2) * scale[0] / fmaxf(sqrtf(a2), 1e-12f);

        float4 feat;
        float* fp = (float*)&feat;
        #pragma unroll
        for (int t = 0; t < 4; ++t) fp[t] = hp[t] + ap[t] * k;

        // Stage feat in per-wave LDS (wave-synchronous; no barrier needed).
        if (eg == 0) *(float4*)&featL[wave * 64 + cg * 4] = feat;
    }

    __syncthreads();   // Wt staging must be visible block-wide before GEMV

    if (active) {
        // GEMV: out[lane] = b[lane] + sum_d feat[d] * Wt[d][lane].
        // 16 b128 broadcast reads (single-bank) + 64 2-way-free b32 Wt reads.
        #pragma unroll
        for (int c4 = 0; c4 < 16; ++c4) {
            float4 f = *(const float4*)&featL[wave * 64 + c4 * 4];
            const float* fq = (const float*)&f;
            #pragma unroll
            for (int t = 0; t < 4; ++t)
                acc = fmaf(fq[t], Wt[(c4 * 4 + t) * 65 + lane], acc);
        }
        __builtin_nontemporal_store(acc, &out[(size_t)n * DD + lane]);
    }
}

extern "C" void kernel_launch(void* const* d_in, const int* in_sizes, int n_in,
                              void* d_out, int out_size, void* d_ws, size_t ws_size,
                              hipStream_t stream) {
    const float* node_feats = (const float*)d_in[0];
    const float* edge_feats = (const float*)d_in[1];
    const float* W          = (const float*)d_in[2];
    const float* b          = (const float*)d_in[3];
    const float* scale      = (const float*)d_in[4];
    const int*   src        = (const int*)d_in[5];
    const int*   dst        = (const int*)d_in[6];
    float*       out        = (float*)d_out;

    int* off = nullptr;
    if (ws_size >= (size_t)(NN + 1) * sizeof(int)) {
        off = (int*)d_ws;
        build_offsets<<<(NE + 255) / 256, 256, 0, stream>>>(dst, off);
    }
    const int blocks = (NN + 3) / 4;   // 4 nodes (waves) per 256-thread block
    genconv_kernel<<<blocks, 256, 0, stream>>>(node_feats, edge_feats, W, b,
                                               scale, src, dst, off, out);
}